// Round 6
// baseline (1773.747 us; speedup 1.0000x reference)
//
#include <hip/hip_runtime.h>
#include <hip/hip_cooperative_groups.h>

namespace cg = cooperative_groups;

#define NN    4096
#define TT    300
#define TPAD  320          // 16 t-chunks * 20
#define TCH   20
#define GRID  256
#define BLOCK 1024
#define NREP  16           // mask replicas (16 blocks per replica)
#define WSTRIDE 18         // LDS fp32 row stride (18 floats; coprime-ish banks, 8B align)
#define HROWS 2048         // w_rec rows resident in LDS (fp32)
#define DECAYF 0.9900498337491681f   // expf(-1/100)
#define THRESHF 10.0f

// dynamic LDS: wlds [2048][18] fp32 (144K, reused as phase1 [4][10][256])
//            | mask_sh [256] u32 | red_sh [16][17] f32
#define WLDS_BYTES (HROWS * WSTRIDE * 4)
#define DSM_BYTES  (WLDS_BYTES + 1024 + 16 * 17 * 4)

// ws: inpT [NN][TPAD] | X [TPAD][NN] | maskrep [NREP][2][256] u32 (t<<16|mask16)
#define WS_REQ ((size_t)NN*TPAD*4*2 + (size_t)NREP*2*256*4)

// Agent-coherent 16B load straight from LLC (bypass L1/L2): sc0 sc1.
__device__ __forceinline__ uint4 llc_load_v4(const uint4* p) {
    uint4 r;
    asm volatile("global_load_dwordx4 %0, %1, off sc0 sc1\n\t"
                 "s_waitcnt vmcnt(0)"
                 : "=v"(r) : "v"(p) : "memory");
    return r;
}

// Write-through store to LLC (no local-L2 dirty residency for pollers to probe).
__device__ __forceinline__ void llc_store_u32(unsigned int* p, unsigned int v) {
    asm volatile("global_store_dword %0, %1, off sc0 sc1"
                 :: "v"(p), "v"(v) : "memory");
}

__global__ __launch_bounds__(BLOCK, 4)
void lif_sim(const int* __restrict__ inp, const float* __restrict__ w,
             const float* __restrict__ w_rec, float* __restrict__ out,
             float* __restrict__ ws)
{
    float* inpT = ws;                                    // [NN][TPAD]
    float* X    = ws + (size_t)NN * TPAD;                // [TPAD][NN]
    unsigned int* maskrep = (unsigned int*)(X + (size_t)TPAD * NN); // [NREP][2][256]

    float* s_all = out;
    float* t_all = out + (size_t)TT * NN;
    float* v_all = out + (size_t)2 * TT * NN;

    cg::grid_group grid = cg::this_grid();
    const int tid  = threadIdx.x;
    const int bid  = blockIdx.x;
    const int gtid = bid * BLOCK + tid;

    extern __shared__ __align__(16) unsigned char dsm[];
    float*        smem    = (float*)dsm;                       // phase1 [4][10][256]
    float*        wlds    = (float*)dsm;                       // phase2 [2048][18] fp32
    unsigned int* mask_sh = (unsigned int*)(dsm + WLDS_BYTES); // [256]
    float*        red_sh  = (float*)(dsm + WLDS_BYTES + 1024); // [16][17]

    // ---------- phase 0: zero mask replicas, build padded transpose inpT ----------
    if (gtid < NREP * 2 * 256) maskrep[gtid] = 0u;   // tag 0 == valid step-0 (no spikes)
    if (gtid < NN * 32) {                    // zero pad cols t in [300,320)
        int j = gtid >> 5, tl = gtid & 31;
        if (tl < TPAD - TT) inpT[(size_t)j * TPAD + TT + tl] = 0.0f;
    }
    for (int idx = gtid; idx < TT * NN; idx += GRID * BLOCK) {
        int t = idx >> 12, j = idx & (NN - 1);           // inp row-major [T][N]
        inpT[(size_t)j * TPAD + t] = (float)inp[idx];
    }
    grid.sync();

    // ---------- phase 1: X = inp @ w (fp32, one j-pass, 20 accumulators) ----------
    {
        const int ct  = bid >> 4;                 // t-chunk 0..15
        const int cc  = bid & 15;                 // col-chunk 0..15
        const int c1  = tid & 255;                // col within chunk
        const int jp  = tid >> 8;                 // j-part 0..3
        const int col = cc * 256 + c1;
        const int t0  = ct * TCH;
        const int j0  = jp * 1024;
        const float* wp = w + col;
        float acc[20];
#pragma unroll
        for (int k = 0; k < 20; ++k) acc[k] = 0.0f;
        for (int j = j0; j < j0 + 1024; ++j) {
            float wj = wp[(size_t)j * NN];                     // coalesced vector load
            const float* iprow = inpT + (size_t)j * TPAD + t0; // uniform -> s_load
#pragma unroll
            for (int k = 0; k < 20; ++k) acc[k] = fmaf(iprow[k], wj, acc[k]);
        }
#pragma unroll
        for (int half = 0; half < 2; ++half) {
#pragma unroll
            for (int k = 0; k < 10; ++k) smem[(jp * 10 + k) * 256 + c1] = acc[half * 10 + k];
            __syncthreads();
            if (jp == 0) {
#pragma unroll
                for (int k = 0; k < 10; ++k) {
                    float s = smem[k * 256 + c1] + smem[(10 + k) * 256 + c1]
                            + smem[(20 + k) * 256 + c1] + smem[(30 + k) * 256 + c1];
                    X[(size_t)(t0 + half * 10 + k) * NN + col] = s;
                }
            }
            __syncthreads();
        }
    }
    grid.sync();

    // ---------- phase 2 setup ----------
    // Column ownership swizzle: under round-robin dispatch (xcd = bid % 8) each
    // XCD owns a CONTIGUOUS 512-col band -> its 32 blocks' upper-row slices are
    // whole 128B L2 lines totalling exactly 4 MiB = one XCD's L2 (hot across
    // steps). Wrong-mapping risk is perf-only.
    const int colgrp = ((bid & 7) << 5) | (bid >> 3);   // 0..255 bijection
    const int col0   = colgrp * 16;
    const int lane = tid & 63;
    const int wave = tid >> 6;                    // 0..15
    const int c    = tid & 15;
    const int r    = tid >> 4;                    // 0..63 (gather group)
    const int col  = col0 + c;

    // Sentinel-init mask_sh: consumers trust per-word tags, and at t=0 this
    // region holds stale phase-1 garbage that could alias tag 0.
    if (tid < 256) mask_sh[tid] = 0xFFFF0000u;

    // stage w_rec rows [0,2048) for our 16 cols into LDS (fp32, stride 18)
    {
        const int srow = tid >> 2;                // 0..255
        const int c4   = (tid & 3) << 2;          // 0,4,8,12
#pragma unroll
        for (int pass = 0; pass < 8; ++pass) {
            const int row = pass * 256 + srow;
            const float4 q = *(const float4*)(w_rec + (size_t)row * NN + col0 + c4);
            float2* dst = (float2*)(wlds + row * WSTRIDE + c4);  // 8B-aligned always
            dst[0] = make_float2(q.x, q.y);
            dst[1] = make_float2(q.z, q.w);
        }
    }
    __syncthreads();                              // sentinel + wlds visible to all

    float v = 0.0f, tv = 1.0f;
    int sprev = 0;
    const float* wrc = w_rec + col + (size_t)(r << 6) * NN;  // groups r>=32: rows>=2048
    const int ldsbase = (r << 6) * WSTRIDE + c;              // groups r<32: LDS rows
    unsigned int* myrep = maskrep + ((bid & 15) * 2) * 256;

    float xreg = 0.0f;
    if (tid < 16) xreg = X[col];                  // X[t=0][col]

    // wave0 is the block's relay AND decider: permanent critical-path role.
    if (wave == 0) __builtin_amdgcn_s_setprio(1);

    for (int t = 0; t < TT; ++t) {
        const unsigned int ut = (unsigned int)t;
        if (wave == 0) {
            // relay: poll own replica; publish EVERY round into LDS (words are
            // self-tagged, so partial/stale publication is harmless). Exit when
            // all 256 words carry tag t.
            const uint4* pp = (const uint4*)(myrep + (t & 1) * 256) + lane;
            volatile unsigned int* d = mask_sh + (lane << 2);
            for (;;) {
                uint4 q = llc_load_v4(pp);
                d[0] = q.x; d[1] = q.y; d[2] = q.z; d[3] = q.w;
                unsigned int bad = ((q.x >> 16) ^ ut) | ((q.y >> 16) ^ ut)
                                 | ((q.z >> 16) ^ ut) | ((q.w >> 16) ^ ut);
                if (__all(bad == 0u)) break;
            }
        } else {
            // consumers: spin on LDS only (no vmem pressure — round-1 lesson).
            // Lane checks the one word it needs; wave reconverges when all 4
            // words of all 4 of its groups are tagged t.
            volatile unsigned int* msv = mask_sh;
            const int widx = (r << 2) + (lane & 3);
            while ((msv[widx] >> 16) != ut) {}
        }

        unsigned long long M;
        {
            volatile unsigned int* ms = mask_sh + (r << 2);
            M = ((unsigned long long)(ms[0] & 0xFFFFu))
              | ((unsigned long long)(ms[1] & 0xFFFFu) << 16)
              | ((unsigned long long)(ms[2] & 0xFFFFu) << 32)
              | ((unsigned long long)(ms[3] & 0xFFFFu) << 48);
        }
        float acc0 = 0.0f, acc1 = 0.0f, acc2 = 0.0f, acc3 = 0.0f;
        if (r < 32) {
            // LDS-resident rows: ~120cy latency, 8-deep ILP
            while (M) {
                float l0, l1 = 0.0f, l2 = 0.0f, l3 = 0.0f,
                      l4 = 0.0f, l5 = 0.0f, l6 = 0.0f, l7 = 0.0f;
                int b0 = __builtin_ctzll(M); M &= M - 1;
                l0 = wlds[ldsbase + b0 * WSTRIDE];
                if (M) { int b = __builtin_ctzll(M); M &= M - 1; l1 = wlds[ldsbase + b * WSTRIDE]; }
                if (M) { int b = __builtin_ctzll(M); M &= M - 1; l2 = wlds[ldsbase + b * WSTRIDE]; }
                if (M) { int b = __builtin_ctzll(M); M &= M - 1; l3 = wlds[ldsbase + b * WSTRIDE]; }
                if (M) { int b = __builtin_ctzll(M); M &= M - 1; l4 = wlds[ldsbase + b * WSTRIDE]; }
                if (M) { int b = __builtin_ctzll(M); M &= M - 1; l5 = wlds[ldsbase + b * WSTRIDE]; }
                if (M) { int b = __builtin_ctzll(M); M &= M - 1; l6 = wlds[ldsbase + b * WSTRIDE]; }
                if (M) { int b = __builtin_ctzll(M); M &= M - 1; l7 = wlds[ldsbase + b * WSTRIDE]; }
                acc0 += l0 + l4; acc1 += l1 + l5; acc2 += l2 + l6; acc3 += l3 + l7;
            }
        } else {
            // L2-resident rows: 16-deep ILP, typically one round
            while (M) {
                float l0,        l1 = 0.0f, l2 = 0.0f, l3 = 0.0f,
                      l4 = 0.0f, l5 = 0.0f, l6 = 0.0f, l7 = 0.0f,
                      l8 = 0.0f, l9 = 0.0f, l10 = 0.0f, l11 = 0.0f,
                      l12 = 0.0f, l13 = 0.0f, l14 = 0.0f, l15 = 0.0f;
                int b0 = __builtin_ctzll(M); M &= M - 1;
                l0 = wrc[(size_t)b0 * NN];
                if (M) { int b = __builtin_ctzll(M); M &= M - 1; l1  = wrc[(size_t)b * NN]; }
                if (M) { int b = __builtin_ctzll(M); M &= M - 1; l2  = wrc[(size_t)b * NN]; }
                if (M) { int b = __builtin_ctzll(M); M &= M - 1; l3  = wrc[(size_t)b * NN]; }
                if (M) { int b = __builtin_ctzll(M); M &= M - 1; l4  = wrc[(size_t)b * NN]; }
                if (M) { int b = __builtin_ctzll(M); M &= M - 1; l5  = wrc[(size_t)b * NN]; }
                if (M) { int b = __builtin_ctzll(M); M &= M - 1; l6  = wrc[(size_t)b * NN]; }
                if (M) { int b = __builtin_ctzll(M); M &= M - 1; l7  = wrc[(size_t)b * NN]; }
                if (M) { int b = __builtin_ctzll(M); M &= M - 1; l8  = wrc[(size_t)b * NN]; }
                if (M) { int b = __builtin_ctzll(M); M &= M - 1; l9  = wrc[(size_t)b * NN]; }
                if (M) { int b = __builtin_ctzll(M); M &= M - 1; l10 = wrc[(size_t)b * NN]; }
                if (M) { int b = __builtin_ctzll(M); M &= M - 1; l11 = wrc[(size_t)b * NN]; }
                if (M) { int b = __builtin_ctzll(M); M &= M - 1; l12 = wrc[(size_t)b * NN]; }
                if (M) { int b = __builtin_ctzll(M); M &= M - 1; l13 = wrc[(size_t)b * NN]; }
                if (M) { int b = __builtin_ctzll(M); M &= M - 1; l14 = wrc[(size_t)b * NN]; }
                if (M) { int b = __builtin_ctzll(M); M &= M - 1; l15 = wrc[(size_t)b * NN]; }
                acc0 += l0 + l4;  acc1 += l1 + l5;  acc2 += l2 + l6;  acc3 += l3 + l7;
                acc0 += l8 + l12; acc1 += l9 + l13; acc2 += l10 + l14; acc3 += l11 + l15;
            }
        }
        // wave-internal pre-reduce across its 4 groups (lanes share c at xor 16/32)
        float part = (acc0 + acc1) + (acc2 + acc3);
        part += __shfl_xor(part, 16, 64);
        part += __shfl_xor(part, 32, 64);
        if (lane < 16) red_sh[wave * 17 + lane] = part;
        __syncthreads();                          // A: the ONE barrier per step

        if (wave == 0) {
            const int cw = lane & 15, h = lane >> 4;        // h = 0..3
            const float* sp = red_sh + h * 4 * 17 + cw;
            float s = (sp[0] + sp[17]) + (sp[34] + sp[51]);
            s += __shfl_xor(s, 16, 64);
            s += __shfl_xor(s, 32, 64);

            bool spike = false;
            if (lane < 16) {
                float x = xreg + s;
                v *= DECAYF;
                if (sprev) x = 0.0f;              // refractory == spiked last step
                v += x;
                spike = v >= THRESHF;
                if (spike) { tv = (float)t * (1.0f / 300.0f); v = 0.0f; }
                sprev = spike ? 1 : 0;
            }
            unsigned long long bal = __ballot(spike);
            unsigned int word = ((unsigned int)(t + 1) << 16)
                              | (unsigned int)(bal & 0xFFFFull);
            const int par = (t + 1) & 1;
            // parallel replica fan-out: 16 lanes store 16 replicas in one issue
            // slot (word is wave-uniform); write-through to LLC.
            if (lane < NREP)
                llc_store_u32(maskrep + (lane * 2 + par) * 256 + colgrp, word);
            if (lane < 16) {
                size_t o = (size_t)t * NN + col;
                // nontemporal: keep the 48KB/step output stream + single-use X
                // reads from evicting the exactly-L2-sized w_rec slices
                __builtin_nontemporal_store(spike ? 1.0f : 0.0f, &s_all[o]);
                __builtin_nontemporal_store(tv, &t_all[o]);
                __builtin_nontemporal_store(v, &v_all[o]);
                if (t + 1 < TT)
                    xreg = __builtin_nontemporal_load(&X[(size_t)(t + 1) * NN + col]);
            }
        }
        // waves 1..15 fall through to the LDS spin for t+1; t+1 tags cannot
        // appear there until wave0 has read red_sh (it publishes them), so the
        // single-buffered red_sh is race-free with one barrier per step.
    }
}

extern "C" void kernel_launch(void* const* d_in, const int* in_sizes, int n_in,
                              void* d_out, int out_size, void* d_ws, size_t ws_size,
                              hipStream_t stream) {
    if (ws_size < WS_REQ) return;   // need ~10.5 MB scratch
    const int*   inp   = (const int*)d_in[0];
    const float* w     = (const float*)d_in[1];
    const float* w_rec = (const float*)d_in[2];
    float* out = (float*)d_out;
    float* ws  = (float*)d_ws;
    // ~146 KiB dynamic LDS needs the opt-in attribute (host-side; capture-safe)
    hipFuncSetAttribute((const void*)lif_sim,
                        hipFuncAttributeMaxDynamicSharedMemorySize, DSM_BYTES);
    void* args[] = {(void*)&inp, (void*)&w, (void*)&w_rec, (void*)&out, (void*)&ws};
    hipLaunchCooperativeKernel((const void*)lif_sim, dim3(GRID), dim3(BLOCK),
                               args, DSM_BYTES, stream);
}

// Round 17
// 1620.347 us; speedup vs baseline: 1.0947x; 1.0947x over previous
//
#include <hip/hip_runtime.h>
#include <hip/hip_cooperative_groups.h>

namespace cg = cooperative_groups;

#define NN    4096
#define TT    300
#define TPAD  320          // 16 t-chunks * 20
#define TCH   20
#define GRID  256
#define BLOCK 1024
#define NREP  16           // mask replicas (16 blocks per replica)
#define WSTRIDE 18         // LDS fp32 row stride (18 floats; coprime-ish banks, 8B align)
#define HROWS 2048         // w_rec rows resident in LDS (fp32)
#define DECAYF 0.9900498337491681f   // expf(-1/100)
#define THRESHF 10.0f

// dynamic LDS: wlds [2048][18] fp32 (144K, reused as phase1 [4][10][256])
//            | mask_sh [256] u32 | red_sh [16][17] f32 | stg [2][4][16] f32
#define WLDS_BYTES (HROWS * WSTRIDE * 4)
#define RED_BYTES  (16 * 17 * 4)
#define STG_BYTES  (2 * 4 * 16 * 4)
#define DSM_BYTES  (WLDS_BYTES + 1024 + RED_BYTES + STG_BYTES)

// ws: inpT [NN][TPAD] | X [TPAD][NN] | maskrep [NREP][2][256] u32 (t<<16|mask16)
#define WS_REQ ((size_t)NN*TPAD*4*2 + (size_t)NREP*2*256*4)

// Agent-coherent 16B load straight from LLC (bypass L1/L2): sc0 sc1.
__device__ __forceinline__ uint4 llc_load_v4(const uint4* p) {
    uint4 r;
    asm volatile("global_load_dwordx4 %0, %1, off sc0 sc1\n\t"
                 "s_waitcnt vmcnt(0)"
                 : "=v"(r) : "v"(p) : "memory");
    return r;
}

// Write-through store to LLC (no local-L2 dirty residency for pollers to probe).
__device__ __forceinline__ void llc_store_u32(unsigned int* p, unsigned int v) {
    asm volatile("global_store_dword %0, %1, off sc0 sc1"
                 :: "v"(p), "v"(v) : "memory");
}

__global__ __launch_bounds__(BLOCK, 4)
void lif_sim(const int* __restrict__ inp, const float* __restrict__ w,
             const float* __restrict__ w_rec, float* __restrict__ out,
             float* __restrict__ ws)
{
    float* inpT = ws;                                    // [NN][TPAD]
    float* X    = ws + (size_t)NN * TPAD;                // [TPAD][NN]
    unsigned int* maskrep = (unsigned int*)(X + (size_t)TPAD * NN); // [NREP][2][256]

    float* s_all = out;
    float* t_all = out + (size_t)TT * NN;
    float* v_all = out + (size_t)2 * TT * NN;

    cg::grid_group grid = cg::this_grid();
    const int tid  = threadIdx.x;
    const int bid  = blockIdx.x;
    const int gtid = bid * BLOCK + tid;

    extern __shared__ __align__(16) unsigned char dsm[];
    float*        smem    = (float*)dsm;                       // phase1 [4][10][256]
    float*        wlds    = (float*)dsm;                       // phase2 [2048][18] fp32
    unsigned int* mask_sh = (unsigned int*)(dsm + WLDS_BYTES); // [256]
    float*        red_sh  = (float*)(dsm + WLDS_BYTES + 1024); // [16][17]
    float*        stg     = (float*)(dsm + WLDS_BYTES + 1024 + RED_BYTES); // [2][4][16]
    // stg fields per parity: 0=s, 1=tv, 2=v (written by wave0 step t, read by
    // wave15 step t+1), 3=x (X[t+1] written by wave15 step t, read by wave0
    // decide t+1). Parity double-buffer removes all same-window aliasing.
    // Every in-loop crossing is ordered by the S/A barrier chain; the only
    // unordered crossing is loop-exit -> epilogue, fixed by a final barrier.

    // ---------- phase 0: zero mask replicas, build padded transpose inpT ----------
    if (gtid < NREP * 2 * 256) maskrep[gtid] = 0u;   // tag 0 == valid step-0 (no spikes)
    if (gtid < NN * 32) {                    // zero pad cols t in [300,320)
        int j = gtid >> 5, tl = gtid & 31;
        if (tl < TPAD - TT) inpT[(size_t)j * TPAD + TT + tl] = 0.0f;
    }
    for (int idx = gtid; idx < TT * NN; idx += GRID * BLOCK) {
        int t = idx >> 12, j = idx & (NN - 1);           // inp row-major [T][N]
        inpT[(size_t)j * TPAD + t] = (float)inp[idx];
    }
    grid.sync();

    // ---------- phase 1: X = inp @ w (fp32, one j-pass, 20 accumulators) ----------
    {
        const int ct  = bid >> 4;                 // t-chunk 0..15
        const int cc  = bid & 15;                 // col-chunk 0..15
        const int c1  = tid & 255;                // col within chunk
        const int jp  = tid >> 8;                 // j-part 0..3
        const int col = cc * 256 + c1;
        const int t0  = ct * TCH;
        const int j0  = jp * 1024;
        const float* wp = w + col;
        float acc[20];
#pragma unroll
        for (int k = 0; k < 20; ++k) acc[k] = 0.0f;
        for (int j = j0; j < j0 + 1024; ++j) {
            float wj = wp[(size_t)j * NN];                     // coalesced vector load
            const float* iprow = inpT + (size_t)j * TPAD + t0; // uniform -> s_load
#pragma unroll
            for (int k = 0; k < 20; ++k) acc[k] = fmaf(iprow[k], wj, acc[k]);
        }
#pragma unroll
        for (int half = 0; half < 2; ++half) {
#pragma unroll
            for (int k = 0; k < 10; ++k) smem[(jp * 10 + k) * 256 + c1] = acc[half * 10 + k];
            __syncthreads();
            if (jp == 0) {
#pragma unroll
                for (int k = 0; k < 10; ++k) {
                    float s = smem[k * 256 + c1] + smem[(10 + k) * 256 + c1]
                            + smem[(20 + k) * 256 + c1] + smem[(30 + k) * 256 + c1];
                    X[(size_t)(t0 + half * 10 + k) * NN + col] = s;
                }
            }
            __syncthreads();
        }
    }
    grid.sync();

    // ---------- phase 2 setup ----------
    // Column ownership swizzle: under round-robin dispatch (xcd = bid % 8) each
    // XCD owns a CONTIGUOUS 512-col band -> its 32 blocks' upper-row slices are
    // whole 128B L2 lines totalling exactly 4 MiB = one XCD's L2 (hot across
    // steps). Wrong-mapping risk is perf-only.
    const int colgrp = ((bid & 7) << 5) | (bid >> 3);   // 0..255 bijection
    const int col0   = colgrp * 16;
    const int lane = tid & 63;
    const int wave = tid >> 6;                    // 0..15
    const int c    = tid & 15;
    const int r    = tid >> 4;                    // 0..63 (gather group)
    const int col  = col0 + c;

    // stage w_rec rows [0,2048) for our 16 cols into LDS (fp32, stride 18)
    {
        const int srow = tid >> 2;                // 0..255
        const int c4   = (tid & 3) << 2;          // 0,4,8,12
#pragma unroll
        for (int pass = 0; pass < 8; ++pass) {
            const int row = pass * 256 + srow;
            const float4 q = *(const float4*)(w_rec + (size_t)row * NN + col0 + c4);
            float2* dst = (float2*)(wlds + row * WSTRIDE + c4);  // 8B-aligned always
            dst[0] = make_float2(q.x, q.y);
            dst[1] = make_float2(q.z, q.w);
        }
    }
    __syncthreads();

    float v = 0.0f, tv = 1.0f;
    int sprev = 0;
    const float* wrc = w_rec + col + (size_t)(r << 6) * NN;  // groups r>=32: rows>=2048
    const int ldsbase = (r << 6) * WSTRIDE + c;              // groups r<32: LDS rows
    unsigned int* myrep = maskrep + ((bid & 15) * 2) * 256;

    float xreg = 0.0f;
    if (tid < 16) xreg = X[col];                  // X[t=0][col] (wave0 lanes 0..15)

    for (int t = 0; t < TT; ++t) {
        // wave0: spin on own replica until all 256 tags == t, then LDS-broadcast.
        // Waves 1..15 park at barrier S (zero memory traffic while waiting).
        // wave0 has NO outstanding HBM stores/loads here (outputs offloaded to
        // wave15), so the poll's vmcnt(0) drains only the fan-out store, which
        // overlaps the poll load in flight.
        if (wave == 0) {
            const uint4* pp = (const uint4*)(myrep + (t & 1) * 256) + lane;
            const unsigned int ut = (unsigned int)t;
            uint4 q;
            for (;;) {
                q = llc_load_v4(pp);
                unsigned int bad = ((q.x >> 16) ^ ut) | ((q.y >> 16) ^ ut)
                                 | ((q.z >> 16) ^ ut) | ((q.w >> 16) ^ ut);
                if (__all(bad == 0u)) break;
            }
            ((uint4*)mask_sh)[lane] = q;
        }
        __syncthreads();                          // S: masks ready in LDS

        unsigned long long M;
        {
            const unsigned int* ms = mask_sh + (r << 2);
            M = ((unsigned long long)(ms[0] & 0xFFFFu))
              | ((unsigned long long)(ms[1] & 0xFFFFu) << 16)
              | ((unsigned long long)(ms[2] & 0xFFFFu) << 32)
              | ((unsigned long long)(ms[3] & 0xFFFFu) << 48);
        }
        float acc0 = 0.0f, acc1 = 0.0f, acc2 = 0.0f, acc3 = 0.0f;
        if (r < 32) {
            // LDS-resident rows: ~120cy latency, 8-deep ILP
            while (M) {
                float l0, l1 = 0.0f, l2 = 0.0f, l3 = 0.0f,
                      l4 = 0.0f, l5 = 0.0f, l6 = 0.0f, l7 = 0.0f;
                int b0 = __builtin_ctzll(M); M &= M - 1;
                l0 = wlds[ldsbase + b0 * WSTRIDE];
                if (M) { int b = __builtin_ctzll(M); M &= M - 1; l1 = wlds[ldsbase + b * WSTRIDE]; }
                if (M) { int b = __builtin_ctzll(M); M &= M - 1; l2 = wlds[ldsbase + b * WSTRIDE]; }
                if (M) { int b = __builtin_ctzll(M); M &= M - 1; l3 = wlds[ldsbase + b * WSTRIDE]; }
                if (M) { int b = __builtin_ctzll(M); M &= M - 1; l4 = wlds[ldsbase + b * WSTRIDE]; }
                if (M) { int b = __builtin_ctzll(M); M &= M - 1; l5 = wlds[ldsbase + b * WSTRIDE]; }
                if (M) { int b = __builtin_ctzll(M); M &= M - 1; l6 = wlds[ldsbase + b * WSTRIDE]; }
                if (M) { int b = __builtin_ctzll(M); M &= M - 1; l7 = wlds[ldsbase + b * WSTRIDE]; }
                acc0 += l0 + l4; acc1 += l1 + l5; acc2 += l2 + l6; acc3 += l3 + l7;
            }
        } else {
            // L2-resident rows: 16-deep ILP, typically one round
            while (M) {
                float l0,        l1 = 0.0f, l2 = 0.0f, l3 = 0.0f,
                      l4 = 0.0f, l5 = 0.0f, l6 = 0.0f, l7 = 0.0f,
                      l8 = 0.0f, l9 = 0.0f, l10 = 0.0f, l11 = 0.0f,
                      l12 = 0.0f, l13 = 0.0f, l14 = 0.0f, l15 = 0.0f;
                int b0 = __builtin_ctzll(M); M &= M - 1;
                l0 = wrc[(size_t)b0 * NN];
                if (M) { int b = __builtin_ctzll(M); M &= M - 1; l1  = wrc[(size_t)b * NN]; }
                if (M) { int b = __builtin_ctzll(M); M &= M - 1; l2  = wrc[(size_t)b * NN]; }
                if (M) { int b = __builtin_ctzll(M); M &= M - 1; l3  = wrc[(size_t)b * NN]; }
                if (M) { int b = __builtin_ctzll(M); M &= M - 1; l4  = wrc[(size_t)b * NN]; }
                if (M) { int b = __builtin_ctzll(M); M &= M - 1; l5  = wrc[(size_t)b * NN]; }
                if (M) { int b = __builtin_ctzll(M); M &= M - 1; l6  = wrc[(size_t)b * NN]; }
                if (M) { int b = __builtin_ctzll(M); M &= M - 1; l7  = wrc[(size_t)b * NN]; }
                if (M) { int b = __builtin_ctzll(M); M &= M - 1; l8  = wrc[(size_t)b * NN]; }
                if (M) { int b = __builtin_ctzll(M); M &= M - 1; l9  = wrc[(size_t)b * NN]; }
                if (M) { int b = __builtin_ctzll(M); M &= M - 1; l10 = wrc[(size_t)b * NN]; }
                if (M) { int b = __builtin_ctzll(M); M &= M - 1; l11 = wrc[(size_t)b * NN]; }
                if (M) { int b = __builtin_ctzll(M); M &= M - 1; l12 = wrc[(size_t)b * NN]; }
                if (M) { int b = __builtin_ctzll(M); M &= M - 1; l13 = wrc[(size_t)b * NN]; }
                if (M) { int b = __builtin_ctzll(M); M &= M - 1; l14 = wrc[(size_t)b * NN]; }
                if (M) { int b = __builtin_ctzll(M); M &= M - 1; l15 = wrc[(size_t)b * NN]; }
                acc0 += l0 + l4;  acc1 += l1 + l5;  acc2 += l2 + l6;  acc3 += l3 + l7;
                acc0 += l8 + l12; acc1 += l9 + l13; acc2 += l10 + l14; acc3 += l11 + l15;
            }
        }
        // wave-internal pre-reduce across its 4 groups (lanes share c at xor 16/32)
        float part = (acc0 + acc1) + (acc2 + acc3);
        part += __shfl_xor(part, 16, 64);
        part += __shfl_xor(part, 32, 64);
        if (lane < 16) red_sh[wave * 17 + lane] = part;
        __syncthreads();                          // A: 16 wave-partials per col in LDS

        if (wave == 0) {
            __builtin_amdgcn_s_setprio(1);        // wave0 is the global critical path
            const int cw = lane & 15, h = lane >> 4;        // h = 0..3
            const float* sp = red_sh + h * 4 * 17 + cw;
            float s = (sp[0] + sp[17]) + (sp[34] + sp[51]);
            s += __shfl_xor(s, 16, 64);
            s += __shfl_xor(s, 32, 64);

            bool spike = false;
            if (lane < 16) {
                // x from register at t=0, else from LDS staging (wave15 wrote
                // X[t] into parity slot t&1 during step t-1; ordered by S/A).
                float xv = (t == 0) ? xreg : stg[(t & 1) * 64 + 48 + lane];
                float x = xv + s;
                v *= DECAYF;
                if (sprev) x = 0.0f;              // refractory == spiked last step
                v += x;
                spike = v >= THRESHF;
                if (spike) { tv = (float)t * (1.0f / 300.0f); v = 0.0f; }
                sprev = spike ? 1 : 0;
            }
            unsigned long long bal = __ballot(spike);
            unsigned int word = ((unsigned int)(t + 1) << 16)
                              | (unsigned int)(bal & 0xFFFFull);
            const int par = (t + 1) & 1;
            // parallel replica fan-out: 16 lanes store 16 replicas in one issue
            // slot (word is wave-uniform); write-through to LLC.
            if (lane < NREP)
                llc_store_u32(maskrep + (lane * 2 + par) * 256 + colgrp, word);
            // stage outputs to LDS (parity t&1); wave15 stores them to HBM
            // during step t+1's exchange window. NO global ops on wave0.
            if (lane < 16) {
                float* sg = stg + (t & 1) * 64;
                sg[lane]      = spike ? 1.0f : 0.0f;
                sg[16 + lane] = tv;
                sg[32 + lane] = v;
            }
            __builtin_amdgcn_s_setprio(0);
        }
        if (wave == 15 && lane < 16) {
            // Exchange-window work (hidden behind wave0's poll for t+1):
            // 1) store step t-1's staged outputs (parity (t-1)&1) to HBM.
            if (t >= 1) {
                const float* sg = stg + ((t - 1) & 1) * 64;
                size_t o = (size_t)(t - 1) * NN + col;
                __builtin_nontemporal_store(sg[lane],      &s_all[o]);
                __builtin_nontemporal_store(sg[16 + lane], &t_all[o]);
                __builtin_nontemporal_store(sg[32 + lane], &v_all[o]);
            }
            // 2) prefetch X[t+1] into staging parity (t+1)&1 for wave0's
            //    decide at t+1 (read happens after A(t+1); ordered).
            if (t + 1 < TT) {
                float xg = __builtin_nontemporal_load(&X[(size_t)(t + 1) * NN + col]);
                stg[((t + 1) & 1) * 64 + 48 + lane] = xg;
            }
        }
        // waves 1..15 proceed to S(t+1) and park there (no memory traffic)
    }
    // Order wave0's final staged write (post-A(299), no barrier since) against
    // the epilogue read below — the one crossing the loop's S/A chain misses.
    __syncthreads();
    // epilogue: final step's outputs are still staged — flush them.
    if (wave == 15 && lane < 16) {
        const float* sg = stg + ((TT - 1) & 1) * 64;
        size_t o = (size_t)(TT - 1) * NN + col;
        __builtin_nontemporal_store(sg[lane],      &s_all[o]);
        __builtin_nontemporal_store(sg[16 + lane], &t_all[o]);
        __builtin_nontemporal_store(sg[32 + lane], &v_all[o]);
    }
}

extern "C" void kernel_launch(void* const* d_in, const int* in_sizes, int n_in,
                              void* d_out, int out_size, void* d_ws, size_t ws_size,
                              hipStream_t stream) {
    if (ws_size < WS_REQ) return;   // need ~10.5 MB scratch
    const int*   inp   = (const int*)d_in[0];
    const float* w     = (const float*)d_in[1];
    const float* w_rec = (const float*)d_in[2];
    float* out = (float*)d_out;
    float* ws  = (float*)d_ws;
    // ~146 KiB dynamic LDS needs the opt-in attribute (host-side; capture-safe)
    hipFuncSetAttribute((const void*)lif_sim,
                        hipFuncAttributeMaxDynamicSharedMemorySize, DSM_BYTES);
    void* args[] = {(void*)&inp, (void*)&w, (void*)&w_rec, (void*)&out, (void*)&ws};
    hipLaunchCooperativeKernel((const void*)lif_sim, dim3(GRID), dim3(BLOCK),
                               args, DSM_BYTES, stream);
}